// Round 11
// baseline (578.859 us; speedup 1.0000x reference)
//
#include <hip/hip_runtime.h>
#include <hip/hip_bf16.h>

#define N 8192
#define FD 128
#define LOG2E 1.4426950408889634f
#define CMA 144   // k4a LDS mask row stride
#define CMB 132   // k4b LDS mask row stride

typedef __attribute__((ext_vector_type(4))) float f4;
typedef __attribute__((ext_vector_type(4))) int i32x4;
typedef __attribute__((ext_vector_type(4))) unsigned int u32x4;
typedef __attribute__((ext_vector_type(8))) __bf16 bf16x8;

__device__ __forceinline__ unsigned short bfbits(float x){
  __bf16 b = (__bf16)x;
  return __builtin_bit_cast(unsigned short, b);
}

// ---- KC: linear adj -> bitmask compress (pure stream at HBM roofline) ----
__global__ __launch_bounds__(256) void kc_compress(const int* __restrict__ adj,
                                                   unsigned char* __restrict__ cmask){
  int tid = blockIdx.x*256 + threadIdx.x;
  const int TOT = 2048*256;
  const i32x4* adj4 = (const i32x4*)adj;
  #pragma unroll 4
  for (int k = 0; k < 16; ++k){
    size_t g = (size_t)tid + (size_t)k*TOT;
    i32x4 a = adj4[g*2], b = adj4[g*2+1];
    unsigned v = (a[0]!=0?1u:0u) | (a[1]!=0?2u:0u) | (a[2]!=0?4u:0u) | (a[3]!=0?8u:0u)
               | (b[0]!=0?16u:0u)| (b[1]!=0?32u:0u)| (b[2]!=0?64u:0u)| (b[3]!=0?128u:0u);
    cmask[g] = (unsigned char)v;
  }
}

// ---- K12: Wh = h @ W (f32) + Bsw (MFMA-B-swizzled bf16) + fused s1L/s2L tail ----
__global__ __launch_bounds__(256) void k12_wh(const float* __restrict__ h,
                                              const float* __restrict__ W,
                                              const float* __restrict__ a,
                                              unsigned short* __restrict__ Bsw,
                                              float* __restrict__ s1L,
                                              float* __restrict__ s2L){
  __shared__ float Wl[64*128];
  __shared__ float hT[128*33];
  int t = threadIdx.x;
  int i0 = blockIdx.x * 32;
  {
    int r  = t >> 3;
    int k0 = (t & 7) * 16;
    const f4* src = (const f4*)&h[(size_t)(i0 + r)*FD + k0];
    #pragma unroll
    for (int q = 0; q < 4; ++q){
      f4 v = src[q];
      #pragma unroll
      for (int e = 0; e < 4; ++e) hT[(k0 + q*4 + e)*33 + r] = v[e];
    }
  }
  int f0 = (t & 31) * 4;
  int r0 = (t >> 5) * 4;
  float acc[4][4] = {};
  for (int half = 0; half < 2; ++half){
    __syncthreads();
    #pragma unroll
    for (int v = 0; v < 8; ++v){
      int idx = (v*256 + t)*4;
      *(f4*)&Wl[idx] = *(const f4*)&W[half*8192 + idx];
    }
    __syncthreads();
    for (int k2 = 0; k2 < 64; ++k2){
      f4 wv = *(const f4*)&Wl[k2*FD + f0];
      f4 hv = *(const f4*)&hT[(half*64 + k2)*33 + r0];
      #pragma unroll
      for (int ri = 0; ri < 4; ++ri)
        #pragma unroll
        for (int fi = 0; fi < 4; ++fi)
          acc[ri][fi] = __builtin_fmaf(hv[ri], wv[fi], acc[ri][fi]);
    }
  }
  int jblk = blockIdx.x;
  int n  = f0 >> 4;
  int fl = f0 & 15;
  #pragma unroll
  for (int ri = 0; ri < 4; ++ri){
    int k = r0 + ri;
    size_t base = (((size_t)jblk*8 + n)*64 + ((k>>3)<<4))*8 + (k&7);
    #pragma unroll
    for (int fi = 0; fi < 4; ++fi)
      Bsw[base + (size_t)(fl + fi)*8] = bfbits(acc[ri][fi]);
  }
  f4 a1v = *(const f4*)&a[f0];
  f4 a2v = *(const f4*)&a[FD + f0];
  float p1[4], p2[4];
  #pragma unroll
  for (int ri = 0; ri < 4; ++ri){
    p1[ri] = 0.f; p2[ri] = 0.f;
    #pragma unroll
    for (int fi = 0; fi < 4; ++fi){
      p1[ri] = __builtin_fmaf(acc[ri][fi], a1v[fi], p1[ri]);
      p2[ri] = __builtin_fmaf(acc[ri][fi], a2v[fi], p2[ri]);
    }
  }
  #pragma unroll
  for (int d = 1; d < 32; d <<= 1){
    #pragma unroll
    for (int ri = 0; ri < 4; ++ri){
      p1[ri] += __shfl_xor(p1[ri], d, 32);
      p2[ri] += __shfl_xor(p2[ri], d, 32);
    }
  }
  if ((t & 31) == 0){
    #pragma unroll
    for (int ri = 0; ri < 4; ++ri){
      s1L[i0 + r0 + ri] = p1[ri] * LOG2E;
      s2L[i0 + r0 + ri] = p2[ri] * LOG2E;
    }
  }
}

// ---------------- K3: M2L = max(s2L) ----------------
__global__ __launch_bounds__(256) void k3_max(const float* __restrict__ s2L,
                                              float* __restrict__ M2L){
  __shared__ float red[4];
  int t = threadIdx.x;
  float m = -3.0e38f;
  for (int i = t; i < N; i += 256) m = fmaxf(m, s2L[i]);
  #pragma unroll
  for (int d = 1; d < 64; d <<= 1) m = fmaxf(m, __shfl_xor(m, d, 64));
  if ((t & 63) == 0) red[t >> 6] = m;
  __syncthreads();
  if (t == 0) *M2L = fmaxf(fmaxf(red[0], red[1]), fmaxf(red[2], red[3]));
}

// ---- K4a (DIAGNOSTIC ARM A): v8 replica — GLDS dbuf + 1 barrier/macro.
// Loop runs TWICE: numerator and denominator both double -> out invariant.
__global__ __launch_bounds__(256,3) void k4a(const unsigned char* __restrict__ cmask,
    const unsigned short* __restrict__ Bsw,
    const float* __restrict__ s1L, const float* __restrict__ s2L,
    const float* __restrict__ M2p,
    float* __restrict__ partial, float* __restrict__ denomp){
  __shared__ __align__(16) unsigned char bswl[2][16384];
  __shared__ __align__(16) unsigned char cml[128*CMA];
  int t = threadIdx.x;
  int wv = t >> 6, lane = t & 63;
  int lrow = lane & 15, lgrp = lane >> 4;
  int bid = blockIdx.x;
  int y  = bid & 7;
  int bx = bid >> 3;
  int jstart = y * 1024;
  const int nmac = 16;
  float M2 = *M2p;
  int i0w = bx*128 + wv*32;
  float s1a = s1L[i0w + lrow], s1b = s1L[i0w + 16 + lrow];
  float ea = s1a + M2, eb = s1b + M2;
  float maL = fmaxf(ea, 0.2f*ea);
  float mbL = fmaxf(eb, 0.2f*eb);

  f4 acc[2][8]; f4 accd[2];
  #pragma unroll
  for (int x = 0; x < 2; ++x){
    accd[x] = (f4){0.f,0.f,0.f,0.f};
    #pragma unroll
    for (int n = 0; n < 8; ++n) acc[x][n] = (f4){0.f,0.f,0.f,0.f};
  }
  u32x4 onesbits = (u32x4){0x3F803F80u,0x3F803F80u,0x3F803F80u,0x3F803F80u};
  bf16x8 ones = __builtin_bit_cast(bf16x8, onesbits);
  const f4* s2v = (const f4*)s2L;

  #define STAGE_BSW64(jb0, b) do {                                             \
    const unsigned int* bg = (const unsigned int*)(Bsw + (size_t)((jb0) >> 5) * 4096); \
    _Pragma("unroll")                                                          \
    for (int q = 0; q < 4; ++q){                                               \
      int chunk = q*4 + wv;                                                    \
      __builtin_amdgcn_global_load_lds(                                        \
        (const __attribute__((address_space(1))) unsigned int*)(bg + (size_t)(chunk*64 + lane)*4), \
        (__attribute__((address_space(3))) unsigned int*)(&bswl[b][0] + chunk*1024), \
        16, 0, 0);                                                             \
    }                                                                          \
  } while(0)

  {
    int rr = t >> 1, hb = (t & 1) * 64;
    const unsigned char* src = cmask + (size_t)(bx*128 + rr)*(N/8) + (jstart >> 3) + hb;
    #pragma unroll
    for (int q = 0; q < 4; ++q)
      *(u32x4*)&cml[rr*CMA + hb + q*16] = *(const u32x4*)(src + q*16);
  }

  int rA = (wv*32 + lrow)*CMA;
  int rB = (wv*32 + 16 + lrow)*CMA;

  for (int rep = 0; rep < 2; ++rep){
    int buf = 0;
    STAGE_BSW64(jstart, 0);
    __syncthreads();
    for (int m = 0; m < nmac; ++m){
      int jb0 = jstart + m*64;
      if (m + 1 < nmac) STAGE_BSW64(jb0 + 64, buf ^ 1);
      #pragma unroll
      for (int js = 0; js < 2; ++js){
        int jb = jb0 + js*32 + lgrp*8;
        f4 ya = s2v[jb >> 2], yb = s2v[(jb >> 2) + 1];
        int cb = m*8 + js*4 + lgrp;
        unsigned mba = cml[rA + cb];
        unsigned mbb = cml[rB + cb];
        bf16x8 fa, fb;
        #pragma unroll
        for (int e = 0; e < 8; ++e){
          float sjv = (e < 4) ? ya[e] : yb[e-4];
          float xa = s1a + sjv,            xb = s1b + sjv;
          float la = fmaxf(xa, 0.2f*xa),   lb = fmaxf(xb, 0.2f*xb);
          float pa = ((mba>>e)&1u) ? __builtin_amdgcn_exp2f(la - maL) : 0.f;
          float pb = ((mbb>>e)&1u) ? __builtin_amdgcn_exp2f(lb - mbL) : 0.f;
          fa[e] = (__bf16)pa; fb[e] = (__bf16)pb;
        }
        accd[0] = __builtin_amdgcn_mfma_f32_16x16x32_bf16(fa, ones, accd[0], 0, 0, 0);
        accd[1] = __builtin_amdgcn_mfma_f32_16x16x32_bf16(fb, ones, accd[1], 0, 0, 0);
        {
          u32x4 b0[4];
          #pragma unroll
          for (int n = 0; n < 4; ++n)
            b0[n] = *(const u32x4*)&bswl[buf][((js*8 + n)*64 + lane)*16];
          #pragma unroll
          for (int n = 0; n < 4; ++n){
            bf16x8 bb = __builtin_bit_cast(bf16x8, b0[n]);
            acc[0][n] = __builtin_amdgcn_mfma_f32_16x16x32_bf16(fa, bb, acc[0][n], 0, 0, 0);
            acc[1][n] = __builtin_amdgcn_mfma_f32_16x16x32_bf16(fb, bb, acc[1][n], 0, 0, 0);
          }
        }
        {
          u32x4 b1[4];
          #pragma unroll
          for (int n = 0; n < 4; ++n)
            b1[n] = *(const u32x4*)&bswl[buf][((js*8 + 4 + n)*64 + lane)*16];
          #pragma unroll
          for (int n = 0; n < 4; ++n){
            bf16x8 bb = __builtin_bit_cast(bf16x8, b1[n]);
            acc[0][4+n] = __builtin_amdgcn_mfma_f32_16x16x32_bf16(fa, bb, acc[0][4+n], 0, 0, 0);
            acc[1][4+n] = __builtin_amdgcn_mfma_f32_16x16x32_bf16(fb, bb, acc[1][4+n], 0, 0, 0);
          }
        }
      }
      __syncthreads();
      buf ^= 1;
    }
  }

  if (lrow == 0){
    #pragma unroll
    for (int x = 0; x < 2; ++x)
      #pragma unroll
      for (int r = 0; r < 4; ++r)
        denomp[(size_t)y*N + i0w + x*16 + lgrp*4 + r] = accd[x][r];
  }
  float* pb = partial + (size_t)y * N * FD;
  #pragma unroll
  for (int x = 0; x < 2; ++x)
    #pragma unroll
    for (int n = 0; n < 8; ++n)
      #pragma unroll
      for (int r = 0; r < 4; ++r)
        pb[(size_t)(i0w + x*16 + lgrp*4 + r)*FD + n*16 + lrow] = acc[x][n][r];
}

// ---- K4b (DIAGNOSTIC ARM B): v9 replica — barrier-free reg loads. Loop x2. ----
__global__ __launch_bounds__(256,4) void k4b(const unsigned char* __restrict__ cmask,
    const unsigned short* __restrict__ Bsw,
    const float* __restrict__ s1L, const float* __restrict__ s2L,
    const float* __restrict__ M2p,
    float* __restrict__ partial, float* __restrict__ denomp){
  __shared__ __align__(16) unsigned char cml[64*CMB];
  __shared__ __align__(16) float s2l[1024];
  int t = threadIdx.x;
  int wv = t >> 6, lane = t & 63;
  int lrow = lane & 15, lgrp = lane >> 4;
  int bid = blockIdx.x;
  int y  = bid & 7;
  int bx = bid >> 3;
  int jstart = y * 1024;
  float M2 = *M2p;
  int i0w = bx*64 + wv*16;
  float s1a = s1L[i0w + lrow];
  float ea = s1a + M2;
  float maL = fmaxf(ea, 0.2f*ea);

  {
    int rr = t >> 2, sg = (t & 3) * 32;
    const unsigned char* src = cmask + (size_t)(bx*64 + rr)*(N/8) + (jstart >> 3) + sg;
    *(u32x4*)&cml[rr*CMB + sg]      = *(const u32x4*)(src);
    *(u32x4*)&cml[rr*CMB + sg + 16] = *(const u32x4*)(src + 16);
  }
  *(f4*)&s2l[t*4] = *(const f4*)&s2L[jstart + t*4];
  __syncthreads();

  f4 acc[8]; f4 accd = (f4){0.f,0.f,0.f,0.f};
  #pragma unroll
  for (int n = 0; n < 8; ++n) acc[n] = (f4){0.f,0.f,0.f,0.f};
  u32x4 onesbits = (u32x4){0x3F803F80u,0x3F803F80u,0x3F803F80u,0x3F803F80u};
  bf16x8 ones = __builtin_bit_cast(bf16x8, onesbits);

  int rA = (wv*16 + lrow)*CMB;
  int jt0 = jstart >> 5;

  for (int rep = 0; rep < 2; ++rep){
    for (int m = 0; m < 16; ++m){
      #pragma unroll
      for (int js = 0; js < 2; ++js){
        int jt = jt0 + m*2 + js;
        int jo = m*64 + js*32 + lgrp*8;
        u32x4 braw[8];
        #pragma unroll
        for (int n = 0; n < 8; ++n)
          braw[n] = *(const u32x4*)&Bsw[(((size_t)jt*8 + n)*64 + lane)*8];
        f4 ya = *(const f4*)&s2l[jo];
        f4 yb = *(const f4*)&s2l[jo+4];
        unsigned mba = cml[rA + m*8 + js*4 + lgrp];
        bf16x8 fa;
        #pragma unroll
        for (int e = 0; e < 8; ++e){
          float sjv = (e < 4) ? ya[e] : yb[e-4];
          float xa = s1a + sjv;
          float la = fmaxf(xa, 0.2f*xa);
          float pa = ((mba>>e)&1u) ? __builtin_amdgcn_exp2f(la - maL) : 0.f;
          fa[e] = (__bf16)pa;
        }
        accd = __builtin_amdgcn_mfma_f32_16x16x32_bf16(fa, ones, accd, 0, 0, 0);
        #pragma unroll
        for (int n = 0; n < 8; ++n)
          acc[n] = __builtin_amdgcn_mfma_f32_16x16x32_bf16(fa,
                     __builtin_bit_cast(bf16x8, braw[n]), acc[n], 0, 0, 0);
      }
    }
  }

  if (lrow == 0){
    #pragma unroll
    for (int r = 0; r < 4; ++r)
      denomp[(size_t)(8 + y)*N + i0w + lgrp*4 + r] = accd[r];
  }
  float* pb = partial + (size_t)(8 + y) * N * FD;
  #pragma unroll
  for (int n = 0; n < 8; ++n)
    #pragma unroll
    for (int r = 0; r < 4; ++r)
      pb[(size_t)(i0w + lgrp*4 + r)*FD + n*16 + lrow] = acc[n][r];
}

// ---------------- K5: combine 16 partial slices (2x from each arm), divide ----
__global__ __launch_bounds__(256) void k5_fin(const float* __restrict__ partial,
    const float* __restrict__ denomp, float* __restrict__ out){
  int g = blockIdx.x*256 + threadIdx.x;
  int i = g >> 7;
  float num = 0.f, den = 0.f;
  for (int c = 0; c < 16; ++c) num += partial[(size_t)c*N*FD + g];
  for (int c = 0; c < 16; ++c) den += denomp[(size_t)c*N + i];
  out[g] = num / den;
}

extern "C" void kernel_launch(void* const* d_in, const int* in_sizes, int n_in,
                              void* d_out, int out_size, void* d_ws, size_t ws_size,
                              hipStream_t stream){
  const float* h   = (const float*)d_in[0];
  const int*   adj = (const int*)d_in[1];
  const float* W   = (const float*)d_in[2];
  const float* a   = (const float*)d_in[3];
  float* out = (float*)d_out;
  char* ws = (char*)d_ws;

  unsigned short* Bsw = (unsigned short*)ws;                 // 2 MB
  float* s1L = (float*)(ws + (size_t)(6u<<20));              // 32 KB
  float* s2L = (float*)(ws + (size_t)(6u<<20) + 32768);      // 32 KB
  float* M2L = (float*)(ws + (size_t)(6u<<20) + 65536);      // 4 B
  float* denomp  = (float*)(ws + (size_t)(7u<<20));          // 16*32 KB
  float* partial = (float*)(ws + (size_t)(8u<<20));          // 16*4 MB = 64 MB
  unsigned char* cmask = (unsigned char*)(ws + (size_t)(80u<<20));  // 8 MB

  hipLaunchKernelGGL(kc_compress, dim3(2048), dim3(256), 0, stream, adj, cmask);
  hipLaunchKernelGGL(k12_wh, dim3(256), dim3(256), 0, stream, h, W, a, Bsw, s1L, s2L);
  hipLaunchKernelGGL(k3_max, dim3(1),   dim3(256), 0, stream, s2L, M2L);
  hipLaunchKernelGGL(k4a, dim3(512),  dim3(256), 0, stream, cmask, Bsw, s1L, s2L, M2L, partial, denomp);
  hipLaunchKernelGGL(k4b, dim3(1024), dim3(256), 0, stream, cmask, Bsw, s1L, s2L, M2L, partial, denomp);
  hipLaunchKernelGGL(k5_fin, dim3(N*FD/256), dim3(256), 0, stream, partial, denomp, out);
}

// Round 12
// 496.237 us; speedup vs baseline: 1.1665x; 1.1665x over previous
//
#include <hip/hip_runtime.h>
#include <hip/hip_bf16.h>

#define N 8192
#define FD 128
#define LOG2E 1.4426950408889634f

typedef __attribute__((ext_vector_type(4))) float f4;
typedef __attribute__((ext_vector_type(4))) int i32x4;
typedef __attribute__((ext_vector_type(4))) unsigned int u32x4;
typedef __attribute__((ext_vector_type(8))) __bf16 bf16x8;

__device__ __forceinline__ unsigned short bfbits(float x){
  __bf16 b = (__bf16)x;
  return __builtin_bit_cast(unsigned short, b);
}

// ---- K12: Wh=h@W -> Bsw (MFMA-B-swizzled bf16) + s1L/s2L + atomicMax(M2u) + ctr=0 ----
// Bsw flat layout: elem(jblk, n, lane, e) at ((jblk*8+n)*64 + lane)*8 + e
__global__ __launch_bounds__(256) void k12_wh(const float* __restrict__ h,
                                              const float* __restrict__ W,
                                              const float* __restrict__ a,
                                              unsigned short* __restrict__ Bsw,
                                              float* __restrict__ s1L,
                                              float* __restrict__ s2L,
                                              unsigned* __restrict__ M2u,
                                              int* __restrict__ ctr){
  __shared__ float Wl[64*128];
  __shared__ float hT[128*33];
  int t = threadIdx.x;
  int i0 = blockIdx.x * 32;
  if (blockIdx.x == 0 && t < 64) ctr[t] = 0;   // zero group counters for k4
  {
    int r  = t >> 3;
    int k0 = (t & 7) * 16;
    const f4* src = (const f4*)&h[(size_t)(i0 + r)*FD + k0];
    #pragma unroll
    for (int q = 0; q < 4; ++q){
      f4 v = src[q];
      #pragma unroll
      for (int e = 0; e < 4; ++e) hT[(k0 + q*4 + e)*33 + r] = v[e];
    }
  }
  int f0 = (t & 31) * 4;
  int r0 = (t >> 5) * 4;
  float acc[4][4] = {};
  for (int half = 0; half < 2; ++half){
    __syncthreads();
    #pragma unroll
    for (int v = 0; v < 8; ++v){
      int idx = (v*256 + t)*4;
      *(f4*)&Wl[idx] = *(const f4*)&W[half*8192 + idx];
    }
    __syncthreads();
    for (int k2 = 0; k2 < 64; ++k2){
      f4 wv = *(const f4*)&Wl[k2*FD + f0];
      f4 hv = *(const f4*)&hT[(half*64 + k2)*33 + r0];
      #pragma unroll
      for (int ri = 0; ri < 4; ++ri)
        #pragma unroll
        for (int fi = 0; fi < 4; ++fi)
          acc[ri][fi] = __builtin_fmaf(hv[ri], wv[fi], acc[ri][fi]);
    }
  }
  int jblk = blockIdx.x;
  int n  = f0 >> 4;
  int fl = f0 & 15;
  #pragma unroll
  for (int ri = 0; ri < 4; ++ri){
    int k = r0 + ri;
    size_t base = (((size_t)jblk*8 + n)*64 + ((k>>3)<<4))*8 + (k&7);
    #pragma unroll
    for (int fi = 0; fi < 4; ++fi)
      Bsw[base + (size_t)(fl + fi)*8] = bfbits(acc[ri][fi]);
  }
  f4 a1v = *(const f4*)&a[f0];
  f4 a2v = *(const f4*)&a[FD + f0];
  float p1[4], p2[4];
  #pragma unroll
  for (int ri = 0; ri < 4; ++ri){
    p1[ri] = 0.f; p2[ri] = 0.f;
    #pragma unroll
    for (int fi = 0; fi < 4; ++fi){
      p1[ri] = __builtin_fmaf(acc[ri][fi], a1v[fi], p1[ri]);
      p2[ri] = __builtin_fmaf(acc[ri][fi], a2v[fi], p2[ri]);
    }
  }
  #pragma unroll
  for (int d = 1; d < 32; d <<= 1){
    #pragma unroll
    for (int ri = 0; ri < 4; ++ri){
      p1[ri] += __shfl_xor(p1[ri], d, 32);
      p2[ri] += __shfl_xor(p2[ri], d, 32);
    }
  }
  if ((t & 31) == 0){
    float lmax = -3.0e38f;
    #pragma unroll
    for (int ri = 0; ri < 4; ++ri){
      float v1 = p1[ri] * LOG2E, v2 = p2[ri] * LOG2E;
      s1L[i0 + r0 + ri] = v1;
      s2L[i0 + r0 + ri] = v2;
      lmax = fmaxf(lmax, v2);
    }
    unsigned b = __builtin_bit_cast(unsigned, lmax);
    unsigned enc = (b >> 31) ? ~b : (b | 0x80000000u);   // order-preserving map
    atomicMax(M2u, enc);   // poison 0xAAAAAAAA decodes to 3e-13 << true max: safe
  }
}

// -- K4 v10: v7 pipeline (inline adj, GLDS dbuf, macro rotation) + fused finisher --
// Block = 256 thr (4 waves), 128 rows x one 1024-j chunk; 512 blocks (64 bx x 8 y).
// Last-of-8 block per bx sums the 8 partial slices and writes out = num/den.
__global__ __launch_bounds__(256,2) void k4_flash(const int* __restrict__ adj,
    const unsigned short* __restrict__ Bsw,
    const float* __restrict__ s1L, const float* __restrict__ s2L,
    const unsigned* __restrict__ M2u,
    float* __restrict__ partial, float* __restrict__ denomp,
    int* __restrict__ ctr, float* __restrict__ out){
  __shared__ __align__(16) unsigned char bswl[2][32768];
  __shared__ __align__(16) unsigned char mknib[2][128*32];
  __shared__ __align__(16) float s2l[2][128];
  __shared__ float denl[128];
  __shared__ int oldl;
  int t = threadIdx.x;
  int wv = t >> 6, lane = t & 63;
  int lrow = lane & 15, lgrp = lane >> 4;
  int bid = blockIdx.x;
  int y  = bid & 7;
  int bx = bid >> 3;
  int jstart = y * 1024;
  const int nmac = 8;           // 8 macros of 128 j
  const int rotm = nmac - 1;
  unsigned mu = *M2u;
  unsigned ub = (mu >> 31) ? (mu ^ 0x80000000u) : ~mu;
  float M2 = __builtin_bit_cast(float, ub);
  int i0w = bx*128 + wv*32;
  float s1a = s1L[i0w + lrow], s1b = s1L[i0w + 16 + lrow];
  float ea = s1a + M2, eb = s1b + M2;
  float maL = fmaxf(ea, 0.2f*ea);
  float mbL = fmaxf(eb, 0.2f*eb);

  f4 acc[2][8]; f4 accd[2];
  #pragma unroll
  for (int x = 0; x < 2; ++x){
    accd[x] = (f4){0.f,0.f,0.f,0.f};
    #pragma unroll
    for (int n = 0; n < 8; ++n) acc[x][n] = (f4){0.f,0.f,0.f,0.f};
  }
  u32x4 onesbits = (u32x4){0x3F803F80u,0x3F803F80u,0x3F803F80u,0x3F803F80u};
  bf16x8 ones = __builtin_bit_cast(bf16x8, onesbits);

  const i32x4* adj4 = (const i32x4*)adj;
  int sr2 = lane >> 5;
  int sj  = lane & 31;
  size_t abase = ((size_t)(bx*128 + wv*32 + sr2) * N) >> 2;
  i32x4 st[16];

  #define STAGE_BSW(jb0, b) do {                                               \
    const unsigned int* bg = (const unsigned int*)(Bsw + (size_t)((jb0) >> 5) * 4096); \
    _Pragma("unroll")                                                          \
    for (int q = 0; q < 8; ++q){                                               \
      int chunk = q*4 + wv;                                                    \
      __builtin_amdgcn_global_load_lds(                                        \
        (const __attribute__((address_space(1))) unsigned int*)(bg + (size_t)(chunk*64 + lane)*4), \
        (__attribute__((address_space(3))) unsigned int*)(&bswl[b][0] + chunk*1024), \
        16, 0, 0);                                                             \
    }                                                                          \
  } while(0)

  #define STAGE_ADJ(jb0) do {                                                  \
    size_t ab = abase + (size_t)((jb0) >> 2) + sj;                             \
    _Pragma("unroll")                                                          \
    for (int e = 0; e < 16; ++e) st[e] = adj4[ab + (size_t)e * 4096];          \
  } while(0)

  #define PACK_MASKS(b) do {                                                   \
    _Pragma("unroll")                                                          \
    for (int e = 0; e < 16; ++e){                                              \
      unsigned nib = (st[e][0] != 0 ? 1u : 0u) | (st[e][1] != 0 ? 2u : 0u)     \
                   | (st[e][2] != 0 ? 4u : 0u) | (st[e][3] != 0 ? 8u : 0u);    \
      int rloc = wv*32 + e*2 + sr2;                                            \
      mknib[b][rloc*32 + sj] = (unsigned char)nib;                             \
    }                                                                          \
  } while(0)

  int buf = 0;
  int jb_first = jstart + (bx & rotm) * 128;
  STAGE_BSW(jb_first, 0);
  STAGE_ADJ(jb_first);
  PACK_MASKS(0);
  if (t < 32) *(f4*)&s2l[0][t*4] = *(const f4*)&s2L[jb_first + t*4];
  __syncthreads();

  for (int m = 0; m < nmac; ++m){
    int jb1 = jstart + ((m + 1 + bx) & rotm) * 128;
    if (m + 1 < nmac){
      STAGE_BSW(jb1, buf ^ 1);
      STAGE_ADJ(jb1);
    }
    #pragma unroll
    for (int js = 0; js < 4; ++js){
      int jo = js*32 + lgrp*8;
      f4 ya = *(const f4*)&s2l[buf][jo];
      f4 yb = *(const f4*)&s2l[buf][jo+4];
      int gb = (js*4 + lgrp)*2;
      unsigned short ua = *(const unsigned short*)&mknib[buf][(wv*32 + lrow)*32 + gb];
      unsigned short ubm = *(const unsigned short*)&mknib[buf][(wv*32 + 16 + lrow)*32 + gb];
      unsigned mba = (ua & 0xFu) | ((ua >> 4) & 0xF0u);
      unsigned mbb = (ubm & 0xFu) | ((ubm >> 4) & 0xF0u);
      bf16x8 fa, fb;
      #pragma unroll
      for (int e = 0; e < 8; ++e){
        float sjv = (e < 4) ? ya[e] : yb[e-4];
        float xa = s1a + sjv,            xb = s1b + sjv;
        float la = fmaxf(xa, 0.2f*xa),   lb = fmaxf(xb, 0.2f*xb);
        float pa = ((mba>>e)&1u) ? __builtin_amdgcn_exp2f(la - maL) : 0.f;
        float pb = ((mbb>>e)&1u) ? __builtin_amdgcn_exp2f(lb - mbL) : 0.f;
        fa[e] = (__bf16)pa; fb[e] = (__bf16)pb;
      }
      accd[0] = __builtin_amdgcn_mfma_f32_16x16x32_bf16(fa, ones, accd[0], 0, 0, 0);
      accd[1] = __builtin_amdgcn_mfma_f32_16x16x32_bf16(fb, ones, accd[1], 0, 0, 0);
      {
        u32x4 b0[4];
        #pragma unroll
        for (int n = 0; n < 4; ++n)
          b0[n] = *(const u32x4*)&bswl[buf][((js*8 + n)*64 + lane)*16];
        #pragma unroll
        for (int n = 0; n < 4; ++n){
          bf16x8 bb = __builtin_bit_cast(bf16x8, b0[n]);
          acc[0][n] = __builtin_amdgcn_mfma_f32_16x16x32_bf16(fa, bb, acc[0][n], 0, 0, 0);
          acc[1][n] = __builtin_amdgcn_mfma_f32_16x16x32_bf16(fb, bb, acc[1][n], 0, 0, 0);
        }
      }
      {
        u32x4 b1[4];
        #pragma unroll
        for (int n = 0; n < 4; ++n)
          b1[n] = *(const u32x4*)&bswl[buf][((js*8 + 4 + n)*64 + lane)*16];
        #pragma unroll
        for (int n = 0; n < 4; ++n){
          bf16x8 bb = __builtin_bit_cast(bf16x8, b1[n]);
          acc[0][4+n] = __builtin_amdgcn_mfma_f32_16x16x32_bf16(fa, bb, acc[0][4+n], 0, 0, 0);
          acc[1][4+n] = __builtin_amdgcn_mfma_f32_16x16x32_bf16(fb, bb, acc[1][4+n], 0, 0, 0);
        }
      }
    }
    if (m + 1 < nmac){
      PACK_MASKS(buf ^ 1);
      if (t < 32) *(f4*)&s2l[buf ^ 1][t*4] = *(const f4*)&s2L[jb1 + t*4];
    }
    __syncthreads();
    buf ^= 1;
  }

  // ---- write this chunk's partial slice ----
  if (lrow == 0){
    #pragma unroll
    for (int x = 0; x < 2; ++x)
      #pragma unroll
      for (int r = 0; r < 4; ++r)
        denomp[(size_t)y*N + i0w + x*16 + lgrp*4 + r] = accd[x][r];
  }
  float* pb = partial + (size_t)y * N * FD;
  #pragma unroll
  for (int x = 0; x < 2; ++x)
    #pragma unroll
    for (int n = 0; n < 8; ++n)
      #pragma unroll
      for (int r = 0; r < 4; ++r)
        pb[(size_t)(i0w + x*16 + lgrp*4 + r)*FD + n*16 + lrow] = acc[x][n][r];

  // ---- last-block-per-bx fused reduction (out = num/den) ----
  __threadfence();                 // agent-scope: make slice visible
  __syncthreads();
  if (t == 0)
    oldl = __hip_atomic_fetch_add(&ctr[bx], 1, __ATOMIC_ACQ_REL, __HIP_MEMORY_SCOPE_AGENT);
  __syncthreads();
  if (oldl == 7){
    __threadfence();               // acquire: invalidate stale cached lines
    if (t < 128){
      float s = 0.f;
      #pragma unroll
      for (int c = 0; c < 8; ++c) s += denomp[(size_t)c*N + bx*128 + t];
      denl[t] = s;
    }
    __syncthreads();
    const f4* p4 = (const f4*)partial;
    f4* out4 = (f4*)out;
    const size_t sl = (size_t)N*FD/4;
    #pragma unroll
    for (int q = 0; q < 16; ++q){
      int idx = q*256 + t;         // f4-index within this bx's 128x128 tile
      size_t g = (size_t)bx*4096 + idx;
      f4 s = (f4){0.f,0.f,0.f,0.f};
      #pragma unroll
      for (int c = 0; c < 8; ++c){
        f4 v = p4[(size_t)c*sl + g];
        #pragma unroll
        for (int e = 0; e < 4; ++e) s[e] += v[e];
      }
      float d = denl[idx >> 5];
      #pragma unroll
      for (int e = 0; e < 4; ++e) s[e] /= d;
      out4[g] = s;
    }
  }
}

extern "C" void kernel_launch(void* const* d_in, const int* in_sizes, int n_in,
                              void* d_out, int out_size, void* d_ws, size_t ws_size,
                              hipStream_t stream){
  const float* h   = (const float*)d_in[0];
  const int*   adj = (const int*)d_in[1];
  const float* W   = (const float*)d_in[2];
  const float* a   = (const float*)d_in[3];
  float* out = (float*)d_out;
  char* ws = (char*)d_ws;

  unsigned short* Bsw = (unsigned short*)ws;                 // 2 MB
  float* s1L = (float*)(ws + (size_t)(6u<<20));              // 32 KB
  float* s2L = (float*)(ws + (size_t)(6u<<20) + 32768);      // 32 KB
  unsigned* M2u = (unsigned*)(ws + (size_t)(6u<<20) + 65536);// 4 B
  int* ctr   = (int*)(ws + (size_t)(6u<<20) + 65600);        // 256 B
  float* denomp  = (float*)(ws + (size_t)(7u<<20));          // 8*32 KB
  float* partial = (float*)(ws + (size_t)(8u<<20));          // 8*4 MB = 32 MB

  hipLaunchKernelGGL(k12_wh, dim3(256), dim3(256), 0, stream,
                     h, W, a, Bsw, s1L, s2L, M2u, ctr);
  hipLaunchKernelGGL(k4_flash, dim3(512), dim3(256), 0, stream,
                     adj, Bsw, s1L, s2L, M2u, partial, denomp, ctr, out);
}